// Round 1
// baseline (286.949 us; speedup 1.0000x reference)
//
#include <hip/hip_runtime.h>
#include <hip/hip_bf16.h>

#define N_NODES 50000
#define E_EDGES 800000
#define F_DIM 128
#define D_DIM 32
#define CUTOFF 5.0f
#define PI_F 3.14159265358979f
#define SCAN_BLOCKS ((N_NODES + 255) / 256)   // 196

#define MLP_BLOCKS ((N_NODES + 63) / 64)       // 782: 64 rows/block, BOTH branches
#define HIST_BLOCKS ((E_EDGES + 255) / 256)    // 3125
#define XPAD 132   // 128+4: float4-aligned rows, conflict-free b128

__device__ __forceinline__ float swishf(float x) { return x / (1.0f + expf(-x)); }

// ---------------------------------------------------------------------------
// Fused: node MLP (blocks [0, MLP_BLOCKS)) + edge histogram (rest).
// R10 restructure (theory: issue-bound, not BW/FMA-bound):
//  - quarter-wave tiles: lane c16 = t&15 owns 8 consecutive cols (2x float4
//    weight loads), group t>>4 owns 4 rows. Per k4: 4 ds_read_b128 +
//    2 global_load_dwordx4 feed 128 FMAs (was 4 LDS + 16 scalar VMEM / 64 FMA).
//    LDS bytes/FMA 1 -> 0.5; weight-load instrs 8x fewer.
//  - BOTH branches in one block (x re-staged from L2 between branches) so qq
//    is stored as full float4 (q_a,q_b,q_a,q_b). Old scheme had separate
//    blocks interleaving 4B halves -> WRITE_SIZE 45.8MB for a 12.8MB array
//    (partial-sector RMW). Predicted ~13.5MB.
// Weights stay LANE-VARYING global loads (vmcnt path) — R5/R7 rule: a
// wave-uniform global operand becomes s_load (out-of-order) and forces
// lgkmcnt(0) drains against ds_read. Do not "simplify" that away.
// ---------------------------------------------------------------------------
__global__ __launch_bounds__(256, 4)
void mlp_hist(const float* __restrict__ x,
              const float* __restrict__ W1a, const float* __restrict__ b1a,
              const float* __restrict__ W2a, const float* __restrict__ b2a,
              const float* __restrict__ W1b, const float* __restrict__ b1b,
              const float* __restrict__ W2b, const float* __restrict__ b2b,
              float* __restrict__ qq,
              const float* __restrict__ rij, const int* __restrict__ dst,
              int* __restrict__ deg) {
  if (blockIdx.x >= MLP_BLOCKS) {
    // ---- histogram part ----
    const int e = (blockIdx.x - MLP_BLOCKS) * 256 + threadIdx.x;
    if (e < E_EDGES && rij[e] < CUTOFF) atomicAdd(&deg[dst[e]], 1);
    return;
  }

  __shared__ float sX[64 * XPAD];   // 33792 B -> 4 blocks/CU

  const int rb = blockIdx.x * 64;
  const int t  = threadIdx.x;
  const int c16 = t & 15;           // col lane within quarter-wave
  const int r0  = (t >> 4) * 4;     // block-local first row (0..60)

  float qo[2][4][2];                // [branch][row][col] layer-2 pre-swish

  // staging helper: 64 rows x 128 cols, 8 float4 per thread, coalesced
  auto stage_x = [&]() {
    const int row = t >> 2;                    // 0..63
    const int kq  = t & 3;                     // 0..3
    const int rowG = min(rb + row, N_NODES - 1);
    const float* xp = x + (size_t)rowG * F_DIM;
#pragma unroll
    for (int p = 0; p < 8; ++p) {
      const int k0 = kq * 4 + p * 16;
      *(float4*)&sX[row * XPAD + k0] = *(const float4*)&xp[k0];
    }
  };

#pragma unroll
  for (int br = 0; br < 2; ++br) {
    const float* __restrict__ W1 = br ? W1b : W1a;
    const float* __restrict__ b1 = br ? b1b : b1a;
    const float* __restrict__ W2 = br ? W2b : W2a;
    const float* __restrict__ b2 = br ? b2b : b2a;

    if (br) __syncthreads();        // prev branch finished reading h from sX
    stage_x();
    __syncthreads();

    // ---- layer 1: acc[4 rows][8 cols], cols 8*c16 .. 8*c16+7 ----
    float acc[4][8];
    {
      const float4 bv0 = *(const float4*)&b1[8 * c16];
      const float4 bv1 = *(const float4*)&b1[8 * c16 + 4];
#pragma unroll
      for (int r = 0; r < 4; ++r) {
        acc[r][0] = bv0.x; acc[r][1] = bv0.y; acc[r][2] = bv0.z; acc[r][3] = bv0.w;
        acc[r][4] = bv1.x; acc[r][5] = bv1.y; acc[r][6] = bv1.z; acc[r][7] = bv1.w;
      }
    }
    {
      const float* xrow  = sX + r0 * XPAD;
      const float* wbase = W1 + 8 * c16;
#pragma unroll 2
      for (int k4 = 0; k4 < 32; ++k4) {
        float4 w0[4], w1[4];
#pragma unroll
        for (int kk = 0; kk < 4; ++kk) {
          const float* wp = wbase + (size_t)(k4 * 4 + kk) * F_DIM;
          w0[kk] = *(const float4*)wp;          // 16 lanes x 16B = 512B coalesced
          w1[kk] = *(const float4*)(wp + 4);
        }
        float4 xv[4];
#pragma unroll
        for (int r = 0; r < 4; ++r)
          xv[r] = *(const float4*)&xrow[r * XPAD + k4 * 4];  // broadcast reads
#pragma unroll
        for (int kk = 0; kk < 4; ++kk) {
#pragma unroll
          for (int r = 0; r < 4; ++r) {
            const float xs = (kk == 0) ? xv[r].x : (kk == 1) ? xv[r].y
                           : (kk == 2) ? xv[r].z : xv[r].w;
            acc[r][0] = fmaf(xs, w0[kk].x, acc[r][0]);
            acc[r][1] = fmaf(xs, w0[kk].y, acc[r][1]);
            acc[r][2] = fmaf(xs, w0[kk].z, acc[r][2]);
            acc[r][3] = fmaf(xs, w0[kk].w, acc[r][3]);
            acc[r][4] = fmaf(xs, w1[kk].x, acc[r][4]);
            acc[r][5] = fmaf(xs, w1[kk].y, acc[r][5]);
            acc[r][6] = fmaf(xs, w1[kk].z, acc[r][6]);
            acc[r][7] = fmaf(xs, w1[kk].w, acc[r][7]);
          }
        }
      }
    }

    __syncthreads();               // all waves done reading sX as x
#pragma unroll
    for (int r = 0; r < 4; ++r) {  // h overlay, two float4 stores per row
      *(float4*)&sX[(r0 + r) * XPAD + 8 * c16] =
          make_float4(swishf(acc[r][0]), swishf(acc[r][1]),
                      swishf(acc[r][2]), swishf(acc[r][3]));
      *(float4*)&sX[(r0 + r) * XPAD + 8 * c16 + 4] =
          make_float4(swishf(acc[r][4]), swishf(acc[r][5]),
                      swishf(acc[r][6]), swishf(acc[r][7]));
    }
    __syncthreads();

    // ---- layer 2: a2[4 rows][2 cols], cols 2*c16, 2*c16+1 ----
    float a2[4][2];
    {
      const float2 b2v = *(const float2*)&b2[2 * c16];
#pragma unroll
      for (int r = 0; r < 4; ++r) { a2[r][0] = b2v.x; a2[r][1] = b2v.y; }
    }
    {
      const float* hrow = sX + r0 * XPAD;
#pragma unroll 2
      for (int k4 = 0; k4 < 32; ++k4) {
        float2 wv[4];
#pragma unroll
        for (int kk = 0; kk < 4; ++kk)
          wv[kk] = *(const float2*)&W2[(size_t)(k4 * 4 + kk) * D_DIM + 2 * c16];
        float4 hv[4];
#pragma unroll
        for (int r = 0; r < 4; ++r)
          hv[r] = *(const float4*)&hrow[r * XPAD + k4 * 4];
#pragma unroll
        for (int kk = 0; kk < 4; ++kk) {
#pragma unroll
          for (int r = 0; r < 4; ++r) {
            const float hs = (kk == 0) ? hv[r].x : (kk == 1) ? hv[r].y
                           : (kk == 2) ? hv[r].z : hv[r].w;
            a2[r][0] = fmaf(hs, wv[kk].x, a2[r][0]);
            a2[r][1] = fmaf(hs, wv[kk].y, a2[r][1]);
          }
        }
      }
    }
#pragma unroll
    for (int r = 0; r < 4; ++r) {
      qo[br][r][0] = a2[r][0];
      qo[br][r][1] = a2[r][1];
    }
  }

  // ---- store qq: full float4 per row -> no partial-sector RMW ----
  // dword layout per row: [2*c + br], c = 2*c16 + {0,1}
#pragma unroll
  for (int r = 0; r < 4; ++r) {
    const int row = rb + r0 + r;
    if (row < N_NODES) {
      *(float4*)&qq[(size_t)row * 64 + 4 * c16] =
          make_float4(swishf(qo[0][r][0]), swishf(qo[1][r][0]),
                      swishf(qo[0][r][1]), swishf(qo[1][r][1]));
    }
  }
}

// --- 3-phase coalesced scan over deg[N] -> row_start[N+1], cursor[N] ---
__global__ __launch_bounds__(256)
void scan_blocksum(const int* __restrict__ deg, int* __restrict__ part) {
  __shared__ int red[256];
  const int t = threadIdx.x;
  const int i = blockIdx.x * 256 + t;
  red[t] = (i < N_NODES) ? deg[i] : 0;
  __syncthreads();
#pragma unroll
  for (int off = 128; off > 0; off >>= 1) {
    if (t < off) red[t] += red[t + off];
    __syncthreads();
  }
  if (t == 0) part[blockIdx.x] = red[0];
}

__global__ __launch_bounds__(256)
void scan_partials(int* __restrict__ part, int* __restrict__ row_start) {
  __shared__ int s[256];
  const int t = threadIdx.x;
  const int v = (t < SCAN_BLOCKS) ? part[t] : 0;
  s[t] = v;
  __syncthreads();
  for (int off = 1; off < 256; off <<= 1) {
    const int u = (t >= off) ? s[t - off] : 0;
    __syncthreads();
    s[t] += u;
    __syncthreads();
  }
  if (t < SCAN_BLOCKS) part[t] = s[t] - v;          // exclusive block offset
  if (t == 255) row_start[N_NODES] = s[255];        // grand total
}

__global__ __launch_bounds__(256)
void scan_write(const int* __restrict__ deg, const int* __restrict__ part,
                int* __restrict__ row_start, int* __restrict__ cursor) {
  __shared__ int s[256];
  const int t = threadIdx.x;
  const int i = blockIdx.x * 256 + t;
  const int v = (i < N_NODES) ? deg[i] : 0;
  s[t] = v;
  __syncthreads();
  for (int off = 1; off < 256; off <<= 1) {
    const int u = (t >= off) ? s[t - off] : 0;
    __syncthreads();
    s[t] += u;
    __syncthreads();
  }
  const int excl = s[t] - v + part[blockIdx.x];
  if (i < N_NODES) { row_start[i] = excl; cursor[i] = excl; }
}

// Reorder surviving edges into per-dst contiguous records:
// rec = (c*vx, c*vy, c*vz, bitcast(src))
__global__ __launch_bounds__(256)
void edge_reorder(const float* __restrict__ rij, const float* __restrict__ vij,
                  const int* __restrict__ src, const int* __restrict__ dst,
                  int* __restrict__ cursor, float4* __restrict__ recs) {
  const int e = blockIdx.x * 256 + threadIdx.x;
  if (e >= E_EDGES) return;
  const float r = rij[e];
  if (r >= CUTOFF) return;
  const float c = 0.5f * (cosf(r * (PI_F / CUTOFF)) + 1.0f);
  const int pos = atomicAdd(&cursor[dst[e]], 1);
  recs[pos] = make_float4(c * vij[3 * e + 0], c * vij[3 * e + 1],
                          c * vij[3 * e + 2], __int_as_float(src[e]));
}

// ---------------------------------------------------------------------------
// Gather + cross + mix: 32 lanes per node (one per d). 4-edge batches to
// break the rec->q dependent-load chain; qq is (q,q2) interleaved float2.
// ---------------------------------------------------------------------------
__global__ __launch_bounds__(256)
void gather_out(const int* __restrict__ row_start, const float4* __restrict__ recs,
                const float2* __restrict__ qq,
                const float* __restrict__ w_mix, const float* __restrict__ b_mix,
                float* __restrict__ out) {
  const int tid = blockIdx.x * 256 + threadIdx.x;  // = n*32 + d
  const int n = tid >> 5;
  const int d = tid & 31;
  if (n >= N_NODES) return;

  const int s0 = row_start[n];
  const int s1 = row_start[n + 1];

  float ax = 0.f, ay = 0.f, az = 0.f, bx = 0.f, by = 0.f, bz = 0.f;
  for (int i = s0; i < s1; i += 4) {
    const int i1 = min(i + 1, s1 - 1);
    const int i2 = min(i + 2, s1 - 1);
    const int i3 = min(i + 3, s1 - 1);
    float4 rc0 = recs[i];
    float4 rc1 = recs[i1];
    float4 rc2 = recs[i2];
    float4 rc3 = recs[i3];
    float2 p0 = qq[__float_as_int(rc0.w) * 32 + d];
    float2 p1 = qq[__float_as_int(rc1.w) * 32 + d];
    float2 p2 = qq[__float_as_int(rc2.w) * 32 + d];
    float2 p3 = qq[__float_as_int(rc3.w) * 32 + d];
    const float m1 = (i + 1 < s1) ? 1.f : 0.f;
    const float m2 = (i + 2 < s1) ? 1.f : 0.f;
    const float m3 = (i + 3 < s1) ? 1.f : 0.f;
    p1.x *= m1; p1.y *= m1;
    p2.x *= m2; p2.y *= m2;
    p3.x *= m3; p3.y *= m3;

    ax += rc0.x * p0.x + rc1.x * p1.x + rc2.x * p2.x + rc3.x * p3.x;
    ay += rc0.y * p0.x + rc1.y * p1.x + rc2.y * p2.x + rc3.y * p3.x;
    az += rc0.z * p0.x + rc1.z * p1.x + rc2.z * p2.x + rc3.z * p3.x;
    bx += rc0.x * p0.y + rc1.x * p1.y + rc2.x * p2.y + rc3.x * p3.y;
    by += rc0.y * p0.y + rc1.y * p1.y + rc2.y * p2.y + rc3.y * p3.y;
    bz += rc0.z * p0.y + rc1.z * p1.y + rc2.z * p2.y + rc3.z * p3.y;
  }

  const float cx = ay * bz - az * by;
  const float cy = az * bx - ax * bz;
  const float cz = ax * by - ay * bx;

  const float w0 = w_mix[0], w1 = w_mix[1], w2 = w_mix[2];
  const float bm = b_mix[0];

  const size_t base = (size_t)tid * 3;
  out[base + 0] = ax * w0 + bx * w1 + cx * w2 + bm;
  out[base + 1] = ay * w0 + by * w1 + cy * w2 + bm;
  out[base + 2] = az * w0 + bz * w1 + cz * w2 + bm;
}

// ---------------------------------------------------------------------------
extern "C" void kernel_launch(void* const* d_in, const int* in_sizes, int n_in,
                              void* d_out, int out_size, void* d_ws, size_t ws_size,
                              hipStream_t stream) {
  const float* x     = (const float*)d_in[0];
  const float* rij   = (const float*)d_in[1];
  const float* vij   = (const float*)d_in[2];
  const int*   src   = (const int*)  d_in[3];
  const int*   dst   = (const int*)  d_in[4];
  const float* W1    = (const float*)d_in[5];
  const float* b1    = (const float*)d_in[6];
  const float* W2    = (const float*)d_in[7];
  const float* b2    = (const float*)d_in[8];
  const float* W1b   = (const float*)d_in[9];
  const float* b1b   = (const float*)d_in[10];
  const float* W2b   = (const float*)d_in[11];
  const float* b2b   = (const float*)d_in[12];
  const float* w_mix = (const float*)d_in[13];
  const float* b_mix = (const float*)d_in[14];
  float* out = (float*)d_out;

  // Workspace: recs [E f4] | qq [N*64] | deg [N] | cursor [N] | row_start [N+1] | part [256]
  float4* recs   = (float4*)d_ws;
  float* qq      = (float*)(recs + E_EDGES);
  int* deg       = (int*)(qq + (size_t)N_NODES * 64);
  int* cursor    = deg + N_NODES;
  int* row_start = cursor + N_NODES;
  int* part      = row_start + N_NODES + 1;

  hipMemsetAsync(deg, 0, sizeof(int) * N_NODES, stream);

  mlp_hist<<<MLP_BLOCKS + HIST_BLOCKS, 256, 0, stream>>>(
      x, W1, b1, W2, b2, W1b, b1b, W2b, b2b, qq, rij, dst, deg);

  scan_blocksum<<<SCAN_BLOCKS, 256, 0, stream>>>(deg, part);
  scan_partials<<<1, 256, 0, stream>>>(part, row_start);
  scan_write<<<SCAN_BLOCKS, 256, 0, stream>>>(deg, part, row_start, cursor);

  const int eb = (E_EDGES + 255) / 256;
  edge_reorder<<<eb, 256, 0, stream>>>(rij, vij, src, dst, cursor, recs);

  gather_out<<<(N_NODES * D_DIM) / 256, 256, 0, stream>>>(
      row_start, recs, (const float2*)qq, w_mix, b_mix, out);
}

// Round 2
// 279.827 us; speedup vs baseline: 1.0254x; 1.0254x over previous
//
#include <hip/hip_runtime.h>
#include <hip/hip_bf16.h>

#define N_NODES 50000
#define E_EDGES 800000
#define F_DIM 128
#define D_DIM 32
#define CUTOFF 5.0f
#define PI_F 3.14159265358979f
#define SCAN_BLOCKS ((N_NODES + 255) / 256)   // 196

#define MLP_BLOCKS ((N_NODES + 31) / 32)       // 1563: 32 rows/block, branches FUSED
#define HIST_BLOCKS ((E_EDGES + 255) / 256)    // 3125
#define XPAD 132   // 128+4: float4-aligned rows, conflict-free b128

__device__ __forceinline__ float swishf(float x) { return x / (1.0f + expf(-x)); }

// ---------------------------------------------------------------------------
// Fused: node MLP (blocks [0, MLP_BLOCKS)) + edge histogram (rest).
// R11 (theory: R10 showed latency/occupancy-bound — 782 blocks = 12 waves/CU,
// VALUBusy 35%, dur flat despite 33% fewer bytes):
//  - 32 rows/block -> 1563 blocks (~6 offered/CU vs 4-block capacity: full).
//  - BOTH branches in ONE k-loop: accA+accB share each ds_read of x
//    (per k4: 4 ds_read_b128 + 8 weight dwordx4 -> 256 FMAs/lane-group).
//    Halves LDS traffic, removes one x staging and 3 barriers.
//  - half-wave cols: lane c=t&31 owns 4 cols (1 dwordx4/branch/kk, 2x dup).
//  - LDS 33.8KB: rows 0-31 = x then hA overlay; rows 32-63 = hB.
// Weights stay LANE-VARYING global loads (vmcnt path) — R5/R7 rule: a
// wave-uniform global operand becomes s_load (out-of-order) and forces
// lgkmcnt(0) drains against ds_read. Do not "simplify" that away.
// ---------------------------------------------------------------------------
__global__ __launch_bounds__(256, 4)
void mlp_hist(const float* __restrict__ x,
              const float* __restrict__ W1a, const float* __restrict__ b1a,
              const float* __restrict__ W2a, const float* __restrict__ b2a,
              const float* __restrict__ W1b, const float* __restrict__ b1b,
              const float* __restrict__ W2b, const float* __restrict__ b2b,
              float* __restrict__ qq,
              const float* __restrict__ rij, const int* __restrict__ dst,
              int* __restrict__ deg) {
  if (blockIdx.x >= MLP_BLOCKS) {
    // ---- histogram part ----
    const int e = (blockIdx.x - MLP_BLOCKS) * 256 + threadIdx.x;
    if (e < E_EDGES && rij[e] < CUTOFF) atomicAdd(&deg[dst[e]], 1);
    return;
  }

  __shared__ float sX[64 * XPAD];   // 33792 B -> 4 blocks/CU

  const int rb = blockIdx.x * 32;
  const int t  = threadIdx.x;
  const int c  = t & 31;            // col lane: L1 cols 4c..4c+3; L2 col c
  const int r0 = (t >> 5) * 4;      // block-local first row (0..28)

  // ---- stage x[rb..rb+31][0..127] -> sX rows 0..31 (coalesced) ----
  {
    const int row = t >> 3;                    // 0..31
    const int kq  = t & 7;                     // 0..7
    const int rowG = min(rb + row, N_NODES - 1);
    const float* xp = x + (size_t)rowG * F_DIM;
#pragma unroll
    for (int p = 0; p < 4; ++p) {
      const int k0 = kq * 4 + p * 32;
      *(float4*)&sX[row * XPAD + k0] = *(const float4*)&xp[k0];
    }
  }
  __syncthreads();

  // ---- layer 1, both branches: acc[4 rows][4 cols] each ----
  float accA[4][4], accB[4][4];
  {
    const float4 ba = *(const float4*)&b1a[4 * c];
    const float4 bb = *(const float4*)&b1b[4 * c];
#pragma unroll
    for (int r = 0; r < 4; ++r) {
      accA[r][0] = ba.x; accA[r][1] = ba.y; accA[r][2] = ba.z; accA[r][3] = ba.w;
      accB[r][0] = bb.x; accB[r][1] = bb.y; accB[r][2] = bb.z; accB[r][3] = bb.w;
    }
  }
  {
    const float* xrow = sX + r0 * XPAD;
    const float* wa_base = W1a + 4 * c;
    const float* wb_base = W1b + 4 * c;
#pragma unroll 2
    for (int k4 = 0; k4 < 32; ++k4) {
      float4 wa[4], wb[4];
#pragma unroll
      for (int kk = 0; kk < 4; ++kk) {
        const size_t off = (size_t)(k4 * 4 + kk) * F_DIM;
        wa[kk] = *(const float4*)(wa_base + off);   // 32 lanes x 16B = 512B
        wb[kk] = *(const float4*)(wb_base + off);
      }
      float4 xv[4];
#pragma unroll
      for (int r = 0; r < 4; ++r)
        xv[r] = *(const float4*)&xrow[r * XPAD + k4 * 4];  // broadcast reads
#pragma unroll
      for (int kk = 0; kk < 4; ++kk) {
#pragma unroll
        for (int r = 0; r < 4; ++r) {
          const float xs = (kk == 0) ? xv[r].x : (kk == 1) ? xv[r].y
                         : (kk == 2) ? xv[r].z : xv[r].w;
          accA[r][0] = fmaf(xs, wa[kk].x, accA[r][0]);
          accA[r][1] = fmaf(xs, wa[kk].y, accA[r][1]);
          accA[r][2] = fmaf(xs, wa[kk].z, accA[r][2]);
          accA[r][3] = fmaf(xs, wa[kk].w, accA[r][3]);
          accB[r][0] = fmaf(xs, wb[kk].x, accB[r][0]);
          accB[r][1] = fmaf(xs, wb[kk].y, accB[r][1]);
          accB[r][2] = fmaf(xs, wb[kk].z, accB[r][2]);
          accB[r][3] = fmaf(xs, wb[kk].w, accB[r][3]);
        }
      }
    }
  }

  __syncthreads();               // all waves done reading sX as x
#pragma unroll
  for (int r = 0; r < 4; ++r) {  // hA overlays x rows; hB in rows 32..63
    *(float4*)&sX[(r0 + r) * XPAD + 4 * c] =
        make_float4(swishf(accA[r][0]), swishf(accA[r][1]),
                    swishf(accA[r][2]), swishf(accA[r][3]));
    *(float4*)&sX[(32 + r0 + r) * XPAD + 4 * c] =
        make_float4(swishf(accB[r][0]), swishf(accB[r][1]),
                    swishf(accB[r][2]), swishf(accB[r][3]));
  }
  __syncthreads();

  // ---- layer 2, both branches: lane = col c of D=32 ----
  float a2A[4], a2B[4];
  {
    const float bA = b2a[c];
    const float bB = b2b[c];
#pragma unroll
    for (int r = 0; r < 4; ++r) { a2A[r] = bA; a2B[r] = bB; }
  }
  {
    const float* hrowA = sX + r0 * XPAD;
    const float* hrowB = sX + (32 + r0) * XPAD;
#pragma unroll 2
    for (int k4 = 0; k4 < 32; ++k4) {
      float wA[4], wB[4];
#pragma unroll
      for (int kk = 0; kk < 4; ++kk) {
        wA[kk] = W2a[(size_t)(k4 * 4 + kk) * D_DIM + c];   // 128B coalesced
        wB[kk] = W2b[(size_t)(k4 * 4 + kk) * D_DIM + c];
      }
      float4 hA[4], hB[4];
#pragma unroll
      for (int r = 0; r < 4; ++r) {
        hA[r] = *(const float4*)&hrowA[r * XPAD + k4 * 4];
        hB[r] = *(const float4*)&hrowB[r * XPAD + k4 * 4];
      }
#pragma unroll
      for (int kk = 0; kk < 4; ++kk) {
#pragma unroll
        for (int r = 0; r < 4; ++r) {
          const float hsA = (kk == 0) ? hA[r].x : (kk == 1) ? hA[r].y
                          : (kk == 2) ? hA[r].z : hA[r].w;
          const float hsB = (kk == 0) ? hB[r].x : (kk == 1) ? hB[r].y
                          : (kk == 2) ? hB[r].z : hB[r].w;
          a2A[r] = fmaf(hsA, wA[kk], a2A[r]);
          a2B[r] = fmaf(hsB, wB[kk], a2B[r]);
        }
      }
    }
  }

  // ---- store qq: float2 (q_a, q_b) per row/col -> full sectors, no RMW ----
#pragma unroll
  for (int r = 0; r < 4; ++r) {
    const int row = rb + r0 + r;
    if (row < N_NODES) {
      *(float2*)&qq[(size_t)row * 64 + 2 * c] =
          make_float2(swishf(a2A[r]), swishf(a2B[r]));
    }
  }
}

// --- 3-phase coalesced scan over deg[N] -> row_start[N+1], cursor[N] ---
__global__ __launch_bounds__(256)
void scan_blocksum(const int* __restrict__ deg, int* __restrict__ part) {
  __shared__ int red[256];
  const int t = threadIdx.x;
  const int i = blockIdx.x * 256 + t;
  red[t] = (i < N_NODES) ? deg[i] : 0;
  __syncthreads();
#pragma unroll
  for (int off = 128; off > 0; off >>= 1) {
    if (t < off) red[t] += red[t + off];
    __syncthreads();
  }
  if (t == 0) part[blockIdx.x] = red[0];
}

__global__ __launch_bounds__(256)
void scan_partials(int* __restrict__ part, int* __restrict__ row_start) {
  __shared__ int s[256];
  const int t = threadIdx.x;
  const int v = (t < SCAN_BLOCKS) ? part[t] : 0;
  s[t] = v;
  __syncthreads();
  for (int off = 1; off < 256; off <<= 1) {
    const int u = (t >= off) ? s[t - off] : 0;
    __syncthreads();
    s[t] += u;
    __syncthreads();
  }
  if (t < SCAN_BLOCKS) part[t] = s[t] - v;          // exclusive block offset
  if (t == 255) row_start[N_NODES] = s[255];        // grand total
}

__global__ __launch_bounds__(256)
void scan_write(const int* __restrict__ deg, const int* __restrict__ part,
                int* __restrict__ row_start, int* __restrict__ cursor) {
  __shared__ int s[256];
  const int t = threadIdx.x;
  const int i = blockIdx.x * 256 + t;
  const int v = (i < N_NODES) ? deg[i] : 0;
  s[t] = v;
  __syncthreads();
  for (int off = 1; off < 256; off <<= 1) {
    const int u = (t >= off) ? s[t - off] : 0;
    __syncthreads();
    s[t] += u;
    __syncthreads();
  }
  const int excl = s[t] - v + part[blockIdx.x];
  if (i < N_NODES) { row_start[i] = excl; cursor[i] = excl; }
}

// Reorder surviving edges into per-dst contiguous records:
// rec = (c*vx, c*vy, c*vz, bitcast(src))
__global__ __launch_bounds__(256)
void edge_reorder(const float* __restrict__ rij, const float* __restrict__ vij,
                  const int* __restrict__ src, const int* __restrict__ dst,
                  int* __restrict__ cursor, float4* __restrict__ recs) {
  const int e = blockIdx.x * 256 + threadIdx.x;
  if (e >= E_EDGES) return;
  const float r = rij[e];
  if (r >= CUTOFF) return;
  const float c = 0.5f * (cosf(r * (PI_F / CUTOFF)) + 1.0f);
  const int pos = atomicAdd(&cursor[dst[e]], 1);
  recs[pos] = make_float4(c * vij[3 * e + 0], c * vij[3 * e + 1],
                          c * vij[3 * e + 2], __int_as_float(src[e]));
}

// ---------------------------------------------------------------------------
// Gather + cross + mix: 32 lanes per node (one per d). 4-edge batches to
// break the rec->q dependent-load chain; qq is (q,q2) interleaved float2.
// ---------------------------------------------------------------------------
__global__ __launch_bounds__(256)
void gather_out(const int* __restrict__ row_start, const float4* __restrict__ recs,
                const float2* __restrict__ qq,
                const float* __restrict__ w_mix, const float* __restrict__ b_mix,
                float* __restrict__ out) {
  const int tid = blockIdx.x * 256 + threadIdx.x;  // = n*32 + d
  const int n = tid >> 5;
  const int d = tid & 31;
  if (n >= N_NODES) return;

  const int s0 = row_start[n];
  const int s1 = row_start[n + 1];

  float ax = 0.f, ay = 0.f, az = 0.f, bx = 0.f, by = 0.f, bz = 0.f;
  for (int i = s0; i < s1; i += 4) {
    const int i1 = min(i + 1, s1 - 1);
    const int i2 = min(i + 2, s1 - 1);
    const int i3 = min(i + 3, s1 - 1);
    float4 rc0 = recs[i];
    float4 rc1 = recs[i1];
    float4 rc2 = recs[i2];
    float4 rc3 = recs[i3];
    float2 p0 = qq[__float_as_int(rc0.w) * 32 + d];
    float2 p1 = qq[__float_as_int(rc1.w) * 32 + d];
    float2 p2 = qq[__float_as_int(rc2.w) * 32 + d];
    float2 p3 = qq[__float_as_int(rc3.w) * 32 + d];
    const float m1 = (i + 1 < s1) ? 1.f : 0.f;
    const float m2 = (i + 2 < s1) ? 1.f : 0.f;
    const float m3 = (i + 3 < s1) ? 1.f : 0.f;
    p1.x *= m1; p1.y *= m1;
    p2.x *= m2; p2.y *= m2;
    p3.x *= m3; p3.y *= m3;

    ax += rc0.x * p0.x + rc1.x * p1.x + rc2.x * p2.x + rc3.x * p3.x;
    ay += rc0.y * p0.x + rc1.y * p1.x + rc2.y * p2.x + rc3.y * p3.x;
    az += rc0.z * p0.x + rc1.z * p1.x + rc2.z * p2.x + rc3.z * p3.x;
    bx += rc0.x * p0.y + rc1.x * p1.y + rc2.x * p2.y + rc3.x * p3.y;
    by += rc0.y * p0.y + rc1.y * p1.y + rc2.y * p2.y + rc3.y * p3.y;
    bz += rc0.z * p0.y + rc1.z * p1.y + rc2.z * p2.y + rc3.z * p3.y;
  }

  const float cx = ay * bz - az * by;
  const float cy = az * bx - ax * bz;
  const float cz = ax * by - ay * bx;

  const float w0 = w_mix[0], w1 = w_mix[1], w2 = w_mix[2];
  const float bm = b_mix[0];

  const size_t base = (size_t)tid * 3;
  out[base + 0] = ax * w0 + bx * w1 + cx * w2 + bm;
  out[base + 1] = ay * w0 + by * w1 + cy * w2 + bm;
  out[base + 2] = az * w0 + bz * w1 + cz * w2 + bm;
}

// ---------------------------------------------------------------------------
extern "C" void kernel_launch(void* const* d_in, const int* in_sizes, int n_in,
                              void* d_out, int out_size, void* d_ws, size_t ws_size,
                              hipStream_t stream) {
  const float* x     = (const float*)d_in[0];
  const float* rij   = (const float*)d_in[1];
  const float* vij   = (const float*)d_in[2];
  const int*   src   = (const int*)  d_in[3];
  const int*   dst   = (const int*)  d_in[4];
  const float* W1    = (const float*)d_in[5];
  const float* b1    = (const float*)d_in[6];
  const float* W2    = (const float*)d_in[7];
  const float* b2    = (const float*)d_in[8];
  const float* W1b   = (const float*)d_in[9];
  const float* b1b   = (const float*)d_in[10];
  const float* W2b   = (const float*)d_in[11];
  const float* b2b   = (const float*)d_in[12];
  const float* w_mix = (const float*)d_in[13];
  const float* b_mix = (const float*)d_in[14];
  float* out = (float*)d_out;

  // Workspace: recs [E f4] | qq [N*64] | deg [N] | cursor [N] | row_start [N+1] | part [256]
  float4* recs   = (float4*)d_ws;
  float* qq      = (float*)(recs + E_EDGES);
  int* deg       = (int*)(qq + (size_t)N_NODES * 64);
  int* cursor    = deg + N_NODES;
  int* row_start = cursor + N_NODES;
  int* part      = row_start + N_NODES + 1;

  hipMemsetAsync(deg, 0, sizeof(int) * N_NODES, stream);

  mlp_hist<<<MLP_BLOCKS + HIST_BLOCKS, 256, 0, stream>>>(
      x, W1, b1, W2, b2, W1b, b1b, W2b, b2b, qq, rij, dst, deg);

  scan_blocksum<<<SCAN_BLOCKS, 256, 0, stream>>>(deg, part);
  scan_partials<<<1, 256, 0, stream>>>(part, row_start);
  scan_write<<<SCAN_BLOCKS, 256, 0, stream>>>(deg, part, row_start, cursor);

  const int eb = (E_EDGES + 255) / 256;
  edge_reorder<<<eb, 256, 0, stream>>>(rij, vij, src, dst, cursor, recs);

  gather_out<<<(N_NODES * D_DIM) / 256, 256, 0, stream>>>(
      row_start, recs, (const float2*)qq, w_mix, b_mix, out);
}